// Round 1
// baseline (185.703 us; speedup 1.0000x reference)
//
#include <hip/hip_runtime.h>
#include <hip/hip_bf16.h>

#define N 4096
#define IN_DIM 256
#define HID 64
#define NHEADS 4
#define OUT_DIM 128
#define LOG2E 1.44269504088896340736f

typedef __attribute__((ext_vector_type(8))) short bf16x8;
typedef __attribute__((ext_vector_type(4))) float f32x4;

// ---------------------------------------------------------------------------
// prep_kernel = gemm1 (blocks 0..511) + mask pack (blocks 512..1535), merged
// so the two independent stages run CONCURRENTLY in one dispatch.
// ---------------------------------------------------------------------------
__global__ __launch_bounds__(256, 4) void prep_kernel(
        const float* __restrict__ x, const float* __restrict__ W,
        const float* __restrict__ a, const int* __restrict__ adj,
        __hip_bfloat16* __restrict__ WhB,
        float* __restrict__ f1, float* __restrict__ f2,
        unsigned* __restrict__ maskT) {
    __shared__ float xs[8 * IN_DIM];
    const int t = threadIdx.x;
    if (blockIdx.x < 512) {
        // ---------------- gemm1 ----------------
        const int c = t & 63, h = t >> 6;
        const int i0 = blockIdx.x * 8;
        const float4* xg = (const float4*)(x + (size_t)i0 * IN_DIM);
        float4* xs4 = (float4*)xs;
        for (int u = t; u < 8 * IN_DIM / 4; u += 256) xs4[u] = xg[u];
        __syncthreads();
        float acc[8];
#pragma unroll
        for (int r = 0; r < 8; r++) acc[r] = 0.f;
        const float* Wp = W + (size_t)h * IN_DIM * HID + c;
        for (int k = 0; k < IN_DIM; k += 4) {
            const float w0 = Wp[(size_t)(k + 0) * HID];
            const float w1 = Wp[(size_t)(k + 1) * HID];
            const float w2 = Wp[(size_t)(k + 2) * HID];
            const float w3 = Wp[(size_t)(k + 3) * HID];
#pragma unroll
            for (int r = 0; r < 8; r++) {
                const float4 xv = *(const float4*)(xs + r * IN_DIM + k);
                acc[r] += xv.x * w0 + xv.y * w1 + xv.z * w2 + xv.w * w3;
            }
        }
        union { ushort u[8]; uint4 v; } cv;
#pragma unroll
        for (int r = 0; r < 8; r++)
            cv.u[r] = __hip_bfloat16_raw(__float2bfloat16(acc[r])).x;
        const int jblk = i0 >> 5, quad = (i0 >> 3) & 3;
        const int lane_idx = (c & 15) + 16 * quad;
        *(uint4*)(WhB + ((((size_t)h * (N / 32) + jblk) * 4 + (c >> 4)) * 64 +
                         lane_idx) * 8) = cv.v;
        const float av1 = a[h * 2 * HID + c];
        const float av2 = a[h * 2 * HID + HID + c];
        float s1[8], s2[8];
#pragma unroll
        for (int r = 0; r < 8; r++) { s1[r] = acc[r] * av1; s2[r] = acc[r] * av2; }
#pragma unroll
        for (int mm = 32; mm > 0; mm >>= 1) {
#pragma unroll
            for (int r = 0; r < 8; r++) {
                s1[r] += __shfl_xor(s1[r], mm, 64);
                s2[r] += __shfl_xor(s2[r], mm, 64);
            }
        }
        if (c == 0) {
#pragma unroll
            for (int r = 0; r < 8; r++) {
                f1[(size_t)h * N + i0 + r] = s1[r] * LOG2E;
                f2[(size_t)h * N + i0 + r] = s2[r] * LOG2E;
            }
        }
    } else {
        // ---------------- mask pack (bit-spread, verified R6) ----------------
        const int lane = t & 63, w = t >> 6;
        const int i = (blockIdx.x - 512) * 4 + w;      // one row per wave
        const int4* arow = (const int4*)(adj + (size_t)i * N);
        for (int jb = 0; jb < N / 256; jb++) {
            const int4 a4 = arow[jb * 64 + lane];
            unsigned long long bal[4];
            bal[0] = __ballot(a4.x > 0);
            bal[1] = __ballot(a4.y > 0);
            bal[2] = __ballot(a4.z > 0);
            bal[3] = __ballot(a4.w > 0);
            if (lane < 8) {
                unsigned word = 0;
#pragma unroll
                for (int e = 0; e < 4; e++) {
                    unsigned xv = (unsigned)(bal[e] >> (8 * lane)) & 0xFFu;
                    xv = (xv | (xv << 12)) & 0x000F000Fu;
                    xv = (xv | (xv << 6))  & 0x03030303u;
                    xv = (xv | (xv << 3))  & 0x11111111u;
                    word |= xv << e;
                }
                maskT[(size_t)(jb * 8 + lane) * N + i] = word;
            }
        }
    }
}

// ---------------------------------------------------------------------------
// Fused attention layer, round 8: occupancy push. Halved row tile (MW) ->
// grid doubles to 512 blocks = 2 blocks/CU = 4 waves/SIMD (was 2). To fit the
// 128-VGPR budget this needs, B-frags are single-staged (loads issued BEFORE
// the ~300cy P-gen VALU block, covering L2 latency); mask/f2 remain 2-stage.
// L1: HEADS=4, DSL=1, MW=2, G=8 -> grid (128,4)=512 blocks, 512 thr.
// L2: HEADS=1, DSL=2, MW=1, G=8 -> grid (256,2)=512 blocks, 512 thr.
// C/D layout (verified): col=lane&15, row=quad*4+reg.
// ---------------------------------------------------------------------------
template <int HEADS, int D, int DSL, int G, int MW>
__global__ __launch_bounds__(G * 64, 4) void attn_fused(
        const unsigned* __restrict__ maskT,             // [N/32][N]
        const __hip_bfloat16* __restrict__ WhB,          // [H][N/32][D/16][64][8]
        const float* __restrict__ f1g, const float* __restrict__ f2g,
        float* __restrict__ outp) {
    constexpr int CTtot = D / 16;
    constexpr int CTT = CTtot / DSL;          // ct-tiles this block owns
    constexpr int CC = (D == 64) ? 1 : 2;     // ct-tiles per epilogue round
    constexpr int KSTEPS = N / (32 * G);
    __shared__ float sh[MW * G * 16 * CC * 17];
    __shared__ float dsh[MW * G * 16];
    const int t = threadIdx.x;
    const int g = t >> 6, lane = t & 63;
    const int m = lane & 15, quad = lane >> 4;
    const int h = blockIdx.y / DSL, slc = blockIdx.y % DSL;
    const int i0 = blockIdx.x * (16 * MW);

    float f1v[MW];
#pragma unroll
    for (int mw = 0; mw < MW; mw++)
        f1v[mw] = f1g[(size_t)h * N + i0 + mw * 16 + m];
    const float* f2p = f2g + (size_t)h * N;
    const bf16x8* whb = (const bf16x8*)WhB + (size_t)h * (N / 32) * CTtot * 64;

    const f32x4 zero = {0.f, 0.f, 0.f, 0.f};
    f32x4 acc[MW][CTT];
    f32x4 sac[MW];
#pragma unroll
    for (int mw = 0; mw < MW; mw++) {
        sac[mw] = zero;
#pragma unroll
        for (int ct = 0; ct < CTT; ct++) acc[mw][ct] = zero;
    }
    const short one_bf = (short)0x3F80;
    const bf16x8 ones = {one_bf, one_bf, one_bf, one_bf,
                         one_bf, one_bf, one_bf, one_bf};

    // -------- K-loop: mask/f2 2-stage pipelined, B-frags single-stage --------
    unsigned mwrd[2][MW];
    float f2v[2][8];
    auto stage_mf = [&](int ks, int b) {
        const int j0 = g * (N / G) + ks * 32;
        const int jw = j0 >> 5;
#pragma unroll
        for (int mw = 0; mw < MW; mw++)
            mwrd[b][mw] = maskT[(size_t)jw * N + i0 + mw * 16 + m];
        const float4 lo = *(const float4*)(f2p + j0 + quad * 8);
        const float4 hi = *(const float4*)(f2p + j0 + quad * 8 + 4);
        f2v[b][0] = lo.x; f2v[b][1] = lo.y; f2v[b][2] = lo.z; f2v[b][3] = lo.w;
        f2v[b][4] = hi.x; f2v[b][5] = hi.y; f2v[b][6] = hi.z; f2v[b][7] = hi.w;
    };

    stage_mf(0, 0);
#pragma unroll 2
    for (int ks = 0; ks < KSTEPS; ks++) {
        const int cur = ks & 1;
        // ---- current-step B frags: issue loads first (hidden under P-gen) ----
        const int jwc = (g * (N / G) + ks * 32) >> 5;
        const bf16x8* bp = whb + ((size_t)jwc * CTtot + slc * CTT) * 64 + lane;
        bf16x8 bfrag[CTT];
#pragma unroll
        for (int ct = 0; ct < CTT; ct++) bfrag[ct] = bp[ct * 64];
        if (ks + 1 < KSTEPS) stage_mf(ks + 1, cur ^ 1);
        // ---- P-gen on current stage ----
        bf16x8 afr[MW];
#pragma unroll
        for (int mw = 0; mw < MW; mw++) {
            const unsigned mword = mwrd[cur][mw] >> (quad * 8);
            float p[8];
#pragma unroll
            for (int e = 0; e < 8; e++) {
                const float tt = f1v[mw] + f2v[cur][e];
                const float lr = fmaxf(tt, 0.5f * tt);        // LeakyReLU(0.5)
                const float pe = __builtin_amdgcn_exp2f(lr);  // log2e folded
                p[e] = ((mword >> e) & 1u) ? pe : 0.f;
            }
            union { bf16x8 v; __hip_bfloat162 h2[4]; } u;
#pragma unroll
            for (int e2 = 0; e2 < 4; e2++)
                u.h2[e2] = __float22bfloat162_rn(
                    make_float2(p[2 * e2], p[2 * e2 + 1]));
            afr[mw] = u.v;
        }
        // ---- MFMAs (B amortized across MW row-tiles) ----
#pragma unroll
        for (int ct = 0; ct < CTT; ct++)
#pragma unroll
            for (int mw = 0; mw < MW; mw++)
                acc[mw][ct] = __builtin_amdgcn_mfma_f32_16x16x32_bf16(
                    afr[mw], bfrag[ct], acc[mw][ct], 0, 0, 0);
#pragma unroll
        for (int mw = 0; mw < MW; mw++)
            sac[mw] = __builtin_amdgcn_mfma_f32_16x16x32_bf16(
                afr[mw], ones, sac[mw], 0, 0, 0);
    }

    // ---- epilogue: LDS cross-group reduction, CC ct-tiles per round ----
#pragma unroll
    for (int rd = 0; rd < CTT / CC; rd++) {
#pragma unroll
        for (int mw = 0; mw < MW; mw++) {
#pragma unroll
            for (int cc = 0; cc < CC; cc++) {
#pragma unroll
                for (int r = 0; r < 4; r++)
                    sh[(((mw * G + g) * 16 + quad * 4 + r) * CC + cc) * 17 + m] =
                        acc[mw][rd * CC + cc][r];
            }
            if (rd == 0 && m == 0) {
#pragma unroll
                for (int r = 0; r < 4; r++)
                    dsh[(mw * G + g) * 16 + quad * 4 + r] = sac[mw][r];
            }
        }
        __syncthreads();
        if (t < 16 * CC * 16) {
            int row, chl;
            if (D == 64) { row = t & 15; chl = (t >> 4) & 15; }
            else         { chl = t & 31; row = (t >> 5) & 15; }
#pragma unroll
            for (int mw = 0; mw < MW; mw++) {
                float av = 0.f, ss = 0.f;
#pragma unroll
                for (int gg = 0; gg < G; gg++) {
                    av += sh[(((mw * G + gg) * 16 + row) * CC + (chl >> 4)) * 17 +
                             (chl & 15)];
                    ss += dsh[(mw * G + gg) * 16 + row];
                }
                float v = av / ss;
                v = (v > 0.f) ? v : (__builtin_amdgcn_exp2f(v * LOG2E) - 1.f);
                const int chg = h * D + slc * (CTT * 16) + rd * CC * 16 + chl;
                const int irow = i0 + mw * 16 + row;
                if (D == 64)
                    outp[(size_t)chg * N + irow] = v;        // h1T[ch][i]
                else
                    outp[(size_t)irow * D + chg] = v;        // out[i][ch]
            }
        }
        __syncthreads();
    }
}

// ---------------------------------------------------------------------------
// gemm2: h1T[256][N] (k-major) @ W_out[256][128] -> WhB2 fragment bf16
// [j/32][ct(8)][lane][e] + fused f1b/f2b (fp32 acc, cross-wave via LDS).
// ---------------------------------------------------------------------------
__global__ void gemm2_kernel(const float* __restrict__ h1T,
                             const float* __restrict__ W2,
                             const float* __restrict__ a2,
                             __hip_bfloat16* __restrict__ WhB2,
                             float* __restrict__ f1, float* __restrict__ f2) {
    __shared__ float hs[8 * IN_DIM];
    __shared__ float fred[2][2][4][2];   // [rh][chalf][r][fn]
    const int t = threadIdx.x;
    const int c = t & 127, rh = t >> 7;
    const int i0 = blockIdx.x * 8;
    for (int u = t; u < 8 * IN_DIM; u += 256) {
        const int r = u & 7, k = u >> 3;
        hs[r * IN_DIM + k] = h1T[(size_t)k * N + i0 + r];
    }
    __syncthreads();
    float acc[4];
#pragma unroll
    for (int rr = 0; rr < 4; rr++) acc[rr] = 0.f;
    for (int k = 0; k < IN_DIM; k += 4) {
        const float w0 = W2[(size_t)(k + 0) * OUT_DIM + c];
        const float w1 = W2[(size_t)(k + 1) * OUT_DIM + c];
        const float w2 = W2[(size_t)(k + 2) * OUT_DIM + c];
        const float w3 = W2[(size_t)(k + 3) * OUT_DIM + c];
#pragma unroll
        for (int rr = 0; rr < 4; rr++) {
            const float4 hv = *(const float4*)(hs + (rh * 4 + rr) * IN_DIM + k);
            acc[rr] += hv.x * w0 + hv.y * w1 + hv.z * w2 + hv.w * w3;
        }
    }
    union { ushort u[4]; uint2 v; } cv;
#pragma unroll
    for (int rr = 0; rr < 4; rr++)
        cv.u[rr] = __hip_bfloat16_raw(__float2bfloat16(acc[rr])).x;
    const int jblk = i0 >> 5, quad = (i0 >> 3) & 3;
    const int lane_idx = (c & 15) + 16 * quad;
    *(uint2*)((__hip_bfloat16*)WhB2 +
              (((size_t)jblk * 8 + (c >> 4)) * 64 + lane_idx) * 8 + rh * 4) = cv.v;
    const float av1 = a2[c], av2 = a2[OUT_DIM + c];
    float s1[4], s2[4];
#pragma unroll
    for (int rr = 0; rr < 4; rr++) { s1[rr] = acc[rr] * av1; s2[rr] = acc[rr] * av2; }
#pragma unroll
    for (int mm = 32; mm > 0; mm >>= 1) {
#pragma unroll
        for (int rr = 0; rr < 4; rr++) {
            s1[rr] += __shfl_xor(s1[rr], mm, 64);
            s2[rr] += __shfl_xor(s2[rr], mm, 64);
        }
    }
    if ((t & 63) == 0) {
        const int chalf = (t >> 6) & 1;
#pragma unroll
        for (int rr = 0; rr < 4; rr++) {
            fred[rh][chalf][rr][0] = s1[rr];
            fred[rh][chalf][rr][1] = s2[rr];
        }
    }
    __syncthreads();
    if (t < 16) {
        const int fn = t & 1, rr = (t >> 1) & 3, rh2 = t >> 3;
        const float v = (fred[rh2][0][rr][fn] + fred[rh2][1][rr][fn]) * LOG2E;
        (fn ? f2 : f1)[i0 + rh2 * 4 + rr] = v;
    }
}

// ---------------------------------------------------------------------------
extern "C" void kernel_launch(void* const* d_in, const int* in_sizes, int n_in,
                              void* d_out, int out_size, void* d_ws, size_t ws_size,
                              hipStream_t stream) {
    const float* x   = (const float*)d_in[0];
    const int*   adj = (const int*)d_in[1];
    const float* Wh_ = (const float*)d_in[2];
    const float* ah  = (const float*)d_in[3];
    const float* W2  = (const float*)d_in[4];
    const float* a2  = (const float*)d_in[5];
    float* out = (float*)d_out;

    float* ws = (float*)d_ws;
    float* f1a = ws;                                    // 4*N
    float* f2a = f1a + (size_t)NHEADS * N;              // 4*N
    float* f1b = f2a + (size_t)NHEADS * N;              // N
    float* f2b = f1b + N;                               // N
    float* h1T = f2b + N;                               // 256*N fp32 (4MB)
    __hip_bfloat16* WhB1 = (__hip_bfloat16*)(h1T + (size_t)IN_DIM * N); // 2MB
    __hip_bfloat16* WhB2 = WhB1 + (size_t)NHEADS * HID * N;            // 1MB
    unsigned* maskT = (unsigned*)(WhB2 + (size_t)OUT_DIM * N);         // 2MB

    // gemm1 (blocks 0..511) + mask pack (512..1535), concurrent
    prep_kernel<<<1536, 256, 0, stream>>>(x, Wh_, ah, adj, WhB1, f1a, f2a, maskT);
    attn_fused<NHEADS, HID, 1, 8, 2>
        <<<dim3(N / 32, NHEADS), 512, 0, stream>>>(maskT, WhB1, f1a, f2a, h1T);
    gemm2_kernel<<<N / 8, 256, 0, stream>>>(h1T, W2, a2, WhB2, f1b, f2b);
    attn_fused<1, OUT_DIM, 2, 8, 1>
        <<<dim3(N / 16, 2), 512, 0, stream>>>(maskT, WhB2, f1b, f2b, out);
}